// Round 1
// baseline (1256.815 us; speedup 1.0000x reference)
//
#include <hip/hip_runtime.h>

#define H       128
#define NNODES  50000
#define NEDGES  640000
#define NTYPES  16
#define EDIM    8

// ---------------------------------------------------------------------------
// proj[t][f] = be[f] + sum_d emb[t][d] * We[d][f]   (16 x 128 lookup table)
// ---------------------------------------------------------------------------
__global__ void proj_kernel(const float* __restrict__ emb,
                            const float* __restrict__ We,
                            const float* __restrict__ be,
                            float* __restrict__ proj) {
    int id = blockIdx.x * blockDim.x + threadIdx.x;   // 0..2047
    if (id >= NTYPES * H) return;
    int t = id >> 7;       // edge type
    int f = id & (H - 1);  // feature
    float acc = be[f];
#pragma unroll
    for (int d = 0; d < EDIM; ++d)
        acc += emb[t * EDIM + d] * We[d * H + f];
    proj[id] = acc;
}

// ---------------------------------------------------------------------------
// scatter: aggr[dst] += relu(x[src] + proj[hash(attr)])
// one thread = (edge, 4 features); 32 consecutive threads cover one edge row
// ---------------------------------------------------------------------------
__global__ void scatter_kernel(const float* __restrict__ x,
                               const int* __restrict__ edge_index,
                               const int* __restrict__ edge_attr,
                               const float* __restrict__ proj,
                               float* __restrict__ aggr) {
    long gid = (long)blockIdx.x * blockDim.x + threadIdx.x;
    if (gid >= (long)NEDGES * (H / 4)) return;
    int e  = (int)(gid >> 5);   // H/4 == 32
    int fq = (int)(gid & 31);

    int src = edge_index[e];
    int dst = edge_index[NEDGES + e];
    int a0 = edge_attr[e * 3 + 0];
    int a1 = edge_attr[e * 3 + 1];
    int a2 = edge_attr[e * 3 + 2];
    int h  = (a0 + 3 * a1 + 7 * a2) & (NTYPES - 1);

    float4 xv = *(const float4*)(x    + (long)src * H + fq * 4);
    float4 pv = *(const float4*)(proj + (long)h   * H + fq * 4);
    float4 m;
    m.x = fmaxf(xv.x + pv.x, 0.0f);
    m.y = fmaxf(xv.y + pv.y, 0.0f);
    m.z = fmaxf(xv.z + pv.z, 0.0f);
    m.w = fmaxf(xv.w + pv.w, 0.0f);

    float* dp = aggr + (long)dst * H + fq * 4;
    atomicAdd(dp + 0, m.x);
    atomicAdd(dp + 1, m.y);
    atomicAdd(dp + 2, m.z);
    atomicAdd(dp + 3, m.w);
}

// ---------------------------------------------------------------------------
// fused row-GEMM: C = op(A' @ W + b), A' = (1+eps)*x + aggr (FIRST) or A (else)
// block: 256 threads, 32 rows x 128 cols tile; thread: 4x4 micro-tile.
// W (64KB) + A-tile (16KB) in LDS -> 2 blocks/CU.
// ---------------------------------------------------------------------------
template <bool FIRST>
__global__ __launch_bounds__(256) void mlp_kernel(
        const float* __restrict__ A,
        const float* __restrict__ aggr,   // FIRST only
        const float* __restrict__ epsp,   // FIRST only
        const float* __restrict__ W,      // [128][128]
        const float* __restrict__ b,      // [128]
        float* __restrict__ C) {
    __shared__ float Wl[H * H];    // 64 KB
    __shared__ float Al[32 * H];   // 16 KB

    const int t = threadIdx.x;
    const int row0 = blockIdx.x * 32;

    // stage W: 4096 float4, 16 per thread
    const float4* W4 = (const float4*)W;
    float4* Wl4 = (float4*)Wl;
#pragma unroll
    for (int i = 0; i < 16; ++i)
        Wl4[t + i * 256] = W4[t + i * 256];

    // stage A tile: 32 rows x 32 float4
    float scale = 0.0f;
    if (FIRST) scale = 1.0f + *epsp;
    float4* Al4 = (float4*)Al;
#pragma unroll
    for (int i = 0; i < 4; ++i) {
        int idx = t + i * 256;          // 0..1023
        int r = idx >> 5, c4 = idx & 31;
        int grow = row0 + r;
        float4 v = make_float4(0.f, 0.f, 0.f, 0.f);
        if (grow < NNODES) {
            v = ((const float4*)(A + (long)grow * H))[c4];
            if (FIRST) {
                float4 g = ((const float4*)(aggr + (long)grow * H))[c4];
                v.x = scale * v.x + g.x;
                v.y = scale * v.y + g.y;
                v.z = scale * v.z + g.z;
                v.w = scale * v.w + g.w;
            }
        }
        Al4[idx] = v;
    }
    __syncthreads();

    const int col0 = (t & 31) * 4;
    const int r0   = (t >> 5) * 4;

    float acc[4][4];
#pragma unroll
    for (int i = 0; i < 4; ++i)
#pragma unroll
        for (int j = 0; j < 4; ++j) acc[i][j] = 0.0f;

#pragma unroll 4
    for (int k = 0; k < H; ++k) {
        float4 w = *(const float4*)(Wl + k * H + col0);
        float a0 = Al[(r0 + 0) * H + k];
        float a1 = Al[(r0 + 1) * H + k];
        float a2 = Al[(r0 + 2) * H + k];
        float a3 = Al[(r0 + 3) * H + k];
        acc[0][0] += a0 * w.x; acc[0][1] += a0 * w.y; acc[0][2] += a0 * w.z; acc[0][3] += a0 * w.w;
        acc[1][0] += a1 * w.x; acc[1][1] += a1 * w.y; acc[1][2] += a1 * w.z; acc[1][3] += a1 * w.w;
        acc[2][0] += a2 * w.x; acc[2][1] += a2 * w.y; acc[2][2] += a2 * w.z; acc[2][3] += a2 * w.w;
        acc[3][0] += a3 * w.x; acc[3][1] += a3 * w.y; acc[3][2] += a3 * w.z; acc[3][3] += a3 * w.w;
    }

    float bb[4];
#pragma unroll
    for (int j = 0; j < 4; ++j) bb[j] = b[col0 + j];

#pragma unroll
    for (int i = 0; i < 4; ++i) {
        int grow = row0 + r0 + i;
        if (grow < NNODES) {
            float4 o;
            o.x = acc[i][0] + bb[0];
            o.y = acc[i][1] + bb[1];
            o.z = acc[i][2] + bb[2];
            o.w = acc[i][3] + bb[3];
            if (FIRST) {
                o.x = fmaxf(o.x, 0.f);
                o.y = fmaxf(o.y, 0.f);
                o.z = fmaxf(o.z, 0.f);
                o.w = fmaxf(o.w, 0.f);
            }
            *(float4*)(C + (long)grow * H + col0) = o;
        }
    }
}

// ---------------------------------------------------------------------------
extern "C" void kernel_launch(void* const* d_in, const int* in_sizes, int n_in,
                              void* d_out, int out_size, void* d_ws, size_t ws_size,
                              hipStream_t stream) {
    const float* x          = (const float*)d_in[0];
    const int*   edge_index = (const int*)  d_in[1];
    const int*   edge_attr  = (const int*)  d_in[2];
    const float* emb        = (const float*)d_in[3];
    const float* We         = (const float*)d_in[4];
    const float* be         = (const float*)d_in[5];
    const float* W1         = (const float*)d_in[6];
    const float* b1         = (const float*)d_in[7];
    const float* W2         = (const float*)d_in[8];
    const float* b2         = (const float*)d_in[9];
    const float* eps        = (const float*)d_in[10];
    float* out = (float*)d_out;

    char* ws = (char*)d_ws;
    float* proj   = (float*)ws;                                        // 8 KB
    float* aggr   = (float*)(ws + 8192);                               // 25.6 MB
    float* hidden = (float*)(ws + 8192 + (size_t)NNODES * H * 4);      // 25.6 MB

    hipMemsetAsync(aggr, 0, (size_t)NNODES * H * sizeof(float), stream);

    proj_kernel<<<(NTYPES * H + 255) / 256, 256, 0, stream>>>(emb, We, be, proj);

    long sthreads = (long)NEDGES * (H / 4);
    scatter_kernel<<<(int)((sthreads + 255) / 256), 256, 0, stream>>>(
        x, edge_index, edge_attr, proj, aggr);

    int gblocks = (NNODES + 31) / 32;
    mlp_kernel<true ><<<gblocks, 256, 0, stream>>>(x, aggr, eps, W1, b1, hidden);
    mlp_kernel<false><<<gblocks, 256, 0, stream>>>(hidden, nullptr, nullptr, W2, b2, out);
}

// Round 2
// 408.728 us; speedup vs baseline: 3.0749x; 3.0749x over previous
//
#include <hip/hip_runtime.h>

#define H       128
#define NNODES  50000
#define NEDGES  640000
#define NTYPES  16
#define EDIM    8

// ---------------------------------------------------------------------------
// proj[t][f] = be[f] + sum_d emb[t][d] * We[d][f]   (16 x 128 lookup table)
// ---------------------------------------------------------------------------
__global__ void proj_kernel(const float* __restrict__ emb,
                            const float* __restrict__ We,
                            const float* __restrict__ be,
                            float* __restrict__ proj) {
    int id = blockIdx.x * blockDim.x + threadIdx.x;   // 0..2047
    if (id >= NTYPES * H) return;
    int t = id >> 7;
    int f = id & (H - 1);
    float acc = be[f];
#pragma unroll
    for (int d = 0; d < EDIM; ++d)
        acc += emb[t * EDIM + d] * We[d * H + f];
    proj[id] = acc;
}

// ---------------------------------------------------------------------------
// histogram of dst degree
// ---------------------------------------------------------------------------
__global__ void hist_kernel(const int* __restrict__ edge_index,
                            int* __restrict__ count) {
    int e = blockIdx.x * blockDim.x + threadIdx.x;
    if (e >= NEDGES) return;
    int dst = edge_index[NEDGES + e];
    atomicAdd(&count[dst], 1);
}

// ---------------------------------------------------------------------------
// single-block exclusive scan over count[0..NNODES) -> offsets, cursor
// ---------------------------------------------------------------------------
__global__ __launch_bounds__(256) void scan_kernel(const int* __restrict__ count,
                                                   int* __restrict__ offsets,
                                                   int* __restrict__ cursor) {
    __shared__ int tsum[256];
    const int t = threadIdx.x;
    const int chunk = (NNODES + 255) / 256;   // 196
    int lo = t * chunk;
    int hi = lo + chunk; if (hi > NNODES) hi = NNODES;
    int s = 0;
    for (int i = lo; i < hi; ++i) s += count[i];
    tsum[t] = s;
    __syncthreads();
    // Hillis-Steele inclusive scan over 256
    for (int off = 1; off < 256; off <<= 1) {
        int v = (t >= off) ? tsum[t - off] : 0;
        __syncthreads();
        tsum[t] += v;
        __syncthreads();
    }
    int run = (t == 0) ? 0 : tsum[t - 1];
    for (int i = lo; i < hi; ++i) {
        offsets[i] = run;
        cursor[i]  = run;
        run += count[i];
    }
    if (t == 255) offsets[NNODES] = run;
}

// ---------------------------------------------------------------------------
// bucket edges by dst: packed[pos] = src | (type << 16)   (src < 2^16)
// ---------------------------------------------------------------------------
__global__ void bucket_kernel(const int* __restrict__ edge_index,
                              const int* __restrict__ edge_attr,
                              int* __restrict__ cursor,
                              unsigned int* __restrict__ packed) {
    int e = blockIdx.x * blockDim.x + threadIdx.x;
    if (e >= NEDGES) return;
    int src = edge_index[e];
    int dst = edge_index[NEDGES + e];
    int a0 = edge_attr[e * 3 + 0];
    int a1 = edge_attr[e * 3 + 1];
    int a2 = edge_attr[e * 3 + 2];
    unsigned int h = (unsigned int)(a0 + 3 * a1 + 7 * a2) & (NTYPES - 1);
    int pos = atomicAdd(&cursor[dst], 1);
    packed[pos] = (unsigned int)src | (h << 16);
}

// ---------------------------------------------------------------------------
// one wave per node: acc = sum_j relu(x[src_j] + proj[type_j]);
// z = (1+eps)*x[n] + acc.   lane holds features [2*lane, 2*lane+1].
// ---------------------------------------------------------------------------
__global__ __launch_bounds__(256) void aggr_z_kernel(
        const float* __restrict__ x,
        const int* __restrict__ offsets,
        const unsigned int* __restrict__ packed,
        const float* __restrict__ proj,
        const float* __restrict__ epsp,
        float* __restrict__ z) {
    __shared__ float projL[NTYPES * H];   // 8 KB
    const int t = threadIdx.x;
#pragma unroll
    for (int i = 0; i < 2; ++i)
        ((float4*)projL)[t + i * 256] = ((const float4*)proj)[t + i * 256];
    __syncthreads();

    const int node = blockIdx.x * 4 + (t >> 6);
    if (node >= NNODES) return;
    const int lane = t & 63;

    const int s = offsets[node];
    const int e = offsets[node + 1];

    float ax = 0.0f, ay = 0.0f;
    int j = s;
    for (; j + 1 < e; j += 2) {
        unsigned int p0 = packed[j];
        unsigned int p1 = packed[j + 1];
        const float2 x0 = *(const float2*)(x + (long)(p0 & 0xffffu) * H + lane * 2);
        const float2 x1 = *(const float2*)(x + (long)(p1 & 0xffffu) * H + lane * 2);
        const float2 q0 = *(const float2*)(projL + (p0 >> 16) * H + lane * 2);
        const float2 q1 = *(const float2*)(projL + (p1 >> 16) * H + lane * 2);
        ax += fmaxf(x0.x + q0.x, 0.0f) + fmaxf(x1.x + q1.x, 0.0f);
        ay += fmaxf(x0.y + q0.y, 0.0f) + fmaxf(x1.y + q1.y, 0.0f);
    }
    if (j < e) {
        unsigned int p0 = packed[j];
        const float2 x0 = *(const float2*)(x + (long)(p0 & 0xffffu) * H + lane * 2);
        const float2 q0 = *(const float2*)(projL + (p0 >> 16) * H + lane * 2);
        ax += fmaxf(x0.x + q0.x, 0.0f);
        ay += fmaxf(x0.y + q0.y, 0.0f);
    }

    const float scale = 1.0f + *epsp;
    const float2 xo = *(const float2*)(x + (long)node * H + lane * 2);
    float2 zo;
    zo.x = scale * xo.x + ax;
    zo.y = scale * xo.y + ay;
    *(float2*)(z + (long)node * H + lane * 2) = zo;
}

// ---------------------------------------------------------------------------
// row-GEMM: C = act(A @ W + b).  32 rows x 128 cols per 256-thread block,
// 4x4 micro-tile per thread.  W (64KB) + A-tile (16KB) in LDS.
// In-place safe (each block reads only the rows it writes; reads complete
// before writes via __syncthreads).
// ---------------------------------------------------------------------------
template <bool RELU>
__global__ __launch_bounds__(256) void mlp_kernel(
        const float* __restrict__ A,
        const float* __restrict__ W,      // [128][128]
        const float* __restrict__ b,      // [128]
        float* __restrict__ C) {
    __shared__ float Wl[H * H];    // 64 KB
    __shared__ float Al[32 * H];   // 16 KB

    const int t = threadIdx.x;
    const int row0 = blockIdx.x * 32;

    const float4* W4 = (const float4*)W;
    float4* Wl4 = (float4*)Wl;
#pragma unroll
    for (int i = 0; i < 16; ++i)
        Wl4[t + i * 256] = W4[t + i * 256];

    float4* Al4 = (float4*)Al;
#pragma unroll
    for (int i = 0; i < 4; ++i) {
        int idx = t + i * 256;          // 0..1023
        int r = idx >> 5, c4 = idx & 31;
        int grow = row0 + r;
        float4 v = make_float4(0.f, 0.f, 0.f, 0.f);
        if (grow < NNODES)
            v = ((const float4*)(A + (long)grow * H))[c4];
        Al4[idx] = v;
    }
    __syncthreads();

    const int col0 = (t & 31) * 4;
    const int r0   = (t >> 5) * 4;

    float acc[4][4];
#pragma unroll
    for (int i = 0; i < 4; ++i)
#pragma unroll
        for (int j = 0; j < 4; ++j) acc[i][j] = 0.0f;

#pragma unroll 4
    for (int k = 0; k < H; ++k) {
        float4 w = *(const float4*)(Wl + k * H + col0);
        float a0 = Al[(r0 + 0) * H + k];
        float a1 = Al[(r0 + 1) * H + k];
        float a2 = Al[(r0 + 2) * H + k];
        float a3 = Al[(r0 + 3) * H + k];
        acc[0][0] += a0 * w.x; acc[0][1] += a0 * w.y; acc[0][2] += a0 * w.z; acc[0][3] += a0 * w.w;
        acc[1][0] += a1 * w.x; acc[1][1] += a1 * w.y; acc[1][2] += a1 * w.z; acc[1][3] += a1 * w.w;
        acc[2][0] += a2 * w.x; acc[2][1] += a2 * w.y; acc[2][2] += a2 * w.z; acc[2][3] += a2 * w.w;
        acc[3][0] += a3 * w.x; acc[3][1] += a3 * w.y; acc[3][2] += a3 * w.z; acc[3][3] += a3 * w.w;
    }

    float bb[4];
#pragma unroll
    for (int j = 0; j < 4; ++j) bb[j] = b[col0 + j];

#pragma unroll
    for (int i = 0; i < 4; ++i) {
        int grow = row0 + r0 + i;
        if (grow < NNODES) {
            float4 o;
            o.x = acc[i][0] + bb[0];
            o.y = acc[i][1] + bb[1];
            o.z = acc[i][2] + bb[2];
            o.w = acc[i][3] + bb[3];
            if (RELU) {
                o.x = fmaxf(o.x, 0.f);
                o.y = fmaxf(o.y, 0.f);
                o.z = fmaxf(o.z, 0.f);
                o.w = fmaxf(o.w, 0.f);
            }
            *(float4*)(C + (long)grow * H + col0) = o;
        }
    }
}

// ---------------------------------------------------------------------------
extern "C" void kernel_launch(void* const* d_in, const int* in_sizes, int n_in,
                              void* d_out, int out_size, void* d_ws, size_t ws_size,
                              hipStream_t stream) {
    const float* x          = (const float*)d_in[0];
    const int*   edge_index = (const int*)  d_in[1];
    const int*   edge_attr  = (const int*)  d_in[2];
    const float* emb        = (const float*)d_in[3];
    const float* We         = (const float*)d_in[4];
    const float* be         = (const float*)d_in[5];
    const float* W1         = (const float*)d_in[6];
    const float* b1         = (const float*)d_in[7];
    const float* W2         = (const float*)d_in[8];
    const float* b2         = (const float*)d_in[9];
    const float* eps        = (const float*)d_in[10];
    float* out = (float*)d_out;

    char* ws = (char*)d_ws;
    size_t off = 0;
    float* proj    = (float*)(ws + off); off += (size_t)NTYPES * H * 4;          // 8 KB
    int*   count   = (int*)  (ws + off); off += (size_t)NNODES * 4;              // 200 KB
    int*   offsets = (int*)  (ws + off); off += (size_t)(NNODES + 4) * 4;        // 200 KB
    int*   cursor  = (int*)  (ws + off); off += (size_t)NNODES * 4;              // 200 KB
    unsigned int* packed = (unsigned int*)(ws + off); off += (size_t)NEDGES * 4; // 2.56 MB
    float* z       = (float*)(ws + off); off += (size_t)NNODES * H * 4;          // 25.6 MB

    hipMemsetAsync(count, 0, (size_t)NNODES * sizeof(int), stream);

    proj_kernel<<<(NTYPES * H + 255) / 256, 256, 0, stream>>>(emb, We, be, proj);

    hist_kernel<<<(NEDGES + 255) / 256, 256, 0, stream>>>(edge_index, count);

    scan_kernel<<<1, 256, 0, stream>>>(count, offsets, cursor);

    bucket_kernel<<<(NEDGES + 255) / 256, 256, 0, stream>>>(
        edge_index, edge_attr, cursor, packed);

    aggr_z_kernel<<<(NNODES + 3) / 4, 256, 0, stream>>>(
        x, offsets, packed, proj, eps, z);

    int gblocks = (NNODES + 31) / 32;
    mlp_kernel<true ><<<gblocks, 256, 0, stream>>>(z, W1, b1, z);    // in-place
    mlp_kernel<false><<<gblocks, 256, 0, stream>>>(z, W2, b2, out);
}

// Round 3
// 301.052 us; speedup vs baseline: 4.1747x; 1.3577x over previous
//
#include <hip/hip_runtime.h>

#define H       128
#define NNODES  50000
#define NEDGES  640000
#define NTYPES  16
#define EDIM    8

#define SCAN_CHUNK 1024
#define NSB ((NNODES + SCAN_CHUNK - 1) / SCAN_CHUNK)   // 49

// ---------------------------------------------------------------------------
// proj[t][f] = be[f] + sum_d emb[t][d] * We[d][f]   (16 x 128 lookup table)
// ---------------------------------------------------------------------------
__global__ void proj_kernel(const float* __restrict__ emb,
                            const float* __restrict__ We,
                            const float* __restrict__ be,
                            float* __restrict__ proj) {
    int id = blockIdx.x * blockDim.x + threadIdx.x;   // 0..2047
    if (id >= NTYPES * H) return;
    int t = id >> 7;
    int f = id & (H - 1);
    float acc = be[f];
#pragma unroll
    for (int d = 0; d < EDIM; ++d)
        acc += emb[t * EDIM + d] * We[d * H + f];
    proj[id] = acc;
}

// ---------------------------------------------------------------------------
// histogram of dst degree
// ---------------------------------------------------------------------------
__global__ void hist_kernel(const int* __restrict__ edge_index,
                            int* __restrict__ count) {
    int e = blockIdx.x * blockDim.x + threadIdx.x;
    if (e >= NEDGES) return;
    int dst = edge_index[NEDGES + e];
    atomicAdd(&count[dst], 1);
}

// ---------------------------------------------------------------------------
// hierarchical scan, phase 1: per-block (1024 elems) sum -> bsum[49]
// ---------------------------------------------------------------------------
__global__ __launch_bounds__(256) void scan_s1(const int* __restrict__ count,
                                               int* __restrict__ bsum) {
    __shared__ int red[256];
    const int t = threadIdx.x;
    const int base = blockIdx.x * SCAN_CHUNK + t * 4;
    int s = 0;
    if (base + 3 < NNODES) {
        int4 v = *(const int4*)(count + base);
        s = v.x + v.y + v.z + v.w;
    } else {
#pragma unroll
        for (int j = 0; j < 4; ++j)
            if (base + j < NNODES) s += count[base + j];
    }
    red[t] = s;
    __syncthreads();
    for (int off = 128; off > 0; off >>= 1) {
        if (t < off) red[t] += red[t + off];
        __syncthreads();
    }
    if (t == 0) bsum[blockIdx.x] = red[0];
}

// ---------------------------------------------------------------------------
// phase 2: one wave exclusive-scans the 49 block sums
// ---------------------------------------------------------------------------
__global__ void scan_s2(const int* __restrict__ bsum,
                        int* __restrict__ boff,
                        int* __restrict__ offsets) {
    int lane = threadIdx.x;   // 64 threads, single wave
    int v = (lane < NSB) ? bsum[lane] : 0;
    int incl = v;
#pragma unroll
    for (int off = 1; off < 64; off <<= 1) {
        int u = __shfl_up(incl, off, 64);
        if (lane >= off) incl += u;
    }
    if (lane < NSB) boff[lane] = incl - v;
    if (lane == 63) offsets[NNODES] = incl;
}

// ---------------------------------------------------------------------------
// phase 3: per-block exclusive scan + block offset -> offsets, cursor
// ---------------------------------------------------------------------------
__global__ __launch_bounds__(256) void scan_s3(const int* __restrict__ count,
                                               const int* __restrict__ boff,
                                               int* __restrict__ offsets,
                                               int* __restrict__ cursor) {
    __shared__ int tsum[256];
    const int t = threadIdx.x;
    const int base = blockIdx.x * SCAN_CHUNK + t * 4;

    int c[4] = {0, 0, 0, 0};
    if (base + 3 < NNODES) {
        int4 v = *(const int4*)(count + base);
        c[0] = v.x; c[1] = v.y; c[2] = v.z; c[3] = v.w;
    } else {
#pragma unroll
        for (int j = 0; j < 4; ++j)
            if (base + j < NNODES) c[j] = count[base + j];
    }
    int s = c[0] + c[1] + c[2] + c[3];
    tsum[t] = s;
    __syncthreads();
    // Hillis-Steele inclusive over 256 thread totals
    for (int off = 1; off < 256; off <<= 1) {
        int v = (t >= off) ? tsum[t - off] : 0;
        __syncthreads();
        tsum[t] += v;
        __syncthreads();
    }
    int run = boff[blockIdx.x] + tsum[t] - s;   // exclusive base for this thread
    int4 o;
    o.x = run;
    o.y = run + c[0];
    o.z = run + c[0] + c[1];
    o.w = run + c[0] + c[1] + c[2];
    if (base + 3 < NNODES) {
        *(int4*)(offsets + base) = o;
        *(int4*)(cursor  + base) = o;
    } else {
        int oo[4] = {o.x, o.y, o.z, o.w};
#pragma unroll
        for (int j = 0; j < 4; ++j)
            if (base + j < NNODES) { offsets[base + j] = oo[j]; cursor[base + j] = oo[j]; }
    }
}

// ---------------------------------------------------------------------------
// bucket edges by dst: packed[pos] = src | (type << 16)   (src < 2^16)
// ---------------------------------------------------------------------------
__global__ void bucket_kernel(const int* __restrict__ edge_index,
                              const int* __restrict__ edge_attr,
                              int* __restrict__ cursor,
                              unsigned int* __restrict__ packed) {
    int e = blockIdx.x * blockDim.x + threadIdx.x;
    if (e >= NEDGES) return;
    int src = edge_index[e];
    int dst = edge_index[NEDGES + e];
    int a0 = edge_attr[e * 3 + 0];
    int a1 = edge_attr[e * 3 + 1];
    int a2 = edge_attr[e * 3 + 2];
    unsigned int h = (unsigned int)(a0 + 3 * a1 + 7 * a2) & (NTYPES - 1);
    int pos = atomicAdd(&cursor[dst], 1);
    packed[pos] = (unsigned int)src | (h << 16);
}

// ---------------------------------------------------------------------------
// one wave per node: acc = sum_j relu(x[src_j] + proj[type_j]);
// z = (1+eps)*x[n] + acc.   lane holds features [2*lane, 2*lane+1].
// ---------------------------------------------------------------------------
__global__ __launch_bounds__(256) void aggr_z_kernel(
        const float* __restrict__ x,
        const int* __restrict__ offsets,
        const unsigned int* __restrict__ packed,
        const float* __restrict__ proj,
        const float* __restrict__ epsp,
        float* __restrict__ z) {
    __shared__ float projL[NTYPES * H];   // 8 KB
    const int t = threadIdx.x;
#pragma unroll
    for (int i = 0; i < 2; ++i)
        ((float4*)projL)[t + i * 256] = ((const float4*)proj)[t + i * 256];
    __syncthreads();

    const int node = blockIdx.x * 4 + (t >> 6);
    if (node >= NNODES) return;
    const int lane = t & 63;

    const int s = offsets[node];
    const int e = offsets[node + 1];

    float ax = 0.0f, ay = 0.0f;
    int j = s;
    for (; j + 1 < e; j += 2) {
        unsigned int p0 = packed[j];
        unsigned int p1 = packed[j + 1];
        const float2 x0 = *(const float2*)(x + (long)(p0 & 0xffffu) * H + lane * 2);
        const float2 x1 = *(const float2*)(x + (long)(p1 & 0xffffu) * H + lane * 2);
        const float2 q0 = *(const float2*)(projL + (p0 >> 16) * H + lane * 2);
        const float2 q1 = *(const float2*)(projL + (p1 >> 16) * H + lane * 2);
        ax += fmaxf(x0.x + q0.x, 0.0f) + fmaxf(x1.x + q1.x, 0.0f);
        ay += fmaxf(x0.y + q0.y, 0.0f) + fmaxf(x1.y + q1.y, 0.0f);
    }
    if (j < e) {
        unsigned int p0 = packed[j];
        const float2 x0 = *(const float2*)(x + (long)(p0 & 0xffffu) * H + lane * 2);
        const float2 q0 = *(const float2*)(projL + (p0 >> 16) * H + lane * 2);
        ax += fmaxf(x0.x + q0.x, 0.0f);
        ay += fmaxf(x0.y + q0.y, 0.0f);
    }

    const float scale = 1.0f + *epsp;
    const float2 xo = *(const float2*)(x + (long)node * H + lane * 2);
    float2 zo;
    zo.x = scale * xo.x + ax;
    zo.y = scale * xo.y + ay;
    *(float2*)(z + (long)node * H + lane * 2) = zo;
}

// ---------------------------------------------------------------------------
// row-GEMM: C = act(A @ W + b).  32 rows x 128 cols per 256-thread block,
// 4x4 micro-tile per thread.  W (64KB) + A-tile (16KB) in LDS.
// ---------------------------------------------------------------------------
template <bool RELU>
__global__ __launch_bounds__(256) void mlp_kernel(
        const float* __restrict__ A,
        const float* __restrict__ W,      // [128][128]
        const float* __restrict__ b,      // [128]
        float* __restrict__ C) {
    __shared__ float Wl[H * H];    // 64 KB
    __shared__ float Al[32 * H];   // 16 KB

    const int t = threadIdx.x;
    const int row0 = blockIdx.x * 32;

    const float4* W4 = (const float4*)W;
    float4* Wl4 = (float4*)Wl;
#pragma unroll
    for (int i = 0; i < 16; ++i)
        Wl4[t + i * 256] = W4[t + i * 256];

    float4* Al4 = (float4*)Al;
#pragma unroll
    for (int i = 0; i < 4; ++i) {
        int idx = t + i * 256;          // 0..1023
        int r = idx >> 5, c4 = idx & 31;
        int grow = row0 + r;
        float4 v = make_float4(0.f, 0.f, 0.f, 0.f);
        if (grow < NNODES)
            v = ((const float4*)(A + (long)grow * H))[c4];
        Al4[idx] = v;
    }
    __syncthreads();

    const int col0 = (t & 31) * 4;
    const int r0   = (t >> 5) * 4;

    float acc[4][4];
#pragma unroll
    for (int i = 0; i < 4; ++i)
#pragma unroll
        for (int j = 0; j < 4; ++j) acc[i][j] = 0.0f;

#pragma unroll 4
    for (int k = 0; k < H; ++k) {
        float4 w = *(const float4*)(Wl + k * H + col0);
        float a0 = Al[(r0 + 0) * H + k];
        float a1 = Al[(r0 + 1) * H + k];
        float a2 = Al[(r0 + 2) * H + k];
        float a3 = Al[(r0 + 3) * H + k];
        acc[0][0] += a0 * w.x; acc[0][1] += a0 * w.y; acc[0][2] += a0 * w.z; acc[0][3] += a0 * w.w;
        acc[1][0] += a1 * w.x; acc[1][1] += a1 * w.y; acc[1][2] += a1 * w.z; acc[1][3] += a1 * w.w;
        acc[2][0] += a2 * w.x; acc[2][1] += a2 * w.y; acc[2][2] += a2 * w.z; acc[2][3] += a2 * w.w;
        acc[3][0] += a3 * w.x; acc[3][1] += a3 * w.y; acc[3][2] += a3 * w.z; acc[3][3] += a3 * w.w;
    }

    float bb[4];
#pragma unroll
    for (int j = 0; j < 4; ++j) bb[j] = b[col0 + j];

#pragma unroll
    for (int i = 0; i < 4; ++i) {
        int grow = row0 + r0 + i;
        if (grow < NNODES) {
            float4 o;
            o.x = acc[i][0] + bb[0];
            o.y = acc[i][1] + bb[1];
            o.z = acc[i][2] + bb[2];
            o.w = acc[i][3] + bb[3];
            if (RELU) {
                o.x = fmaxf(o.x, 0.f);
                o.y = fmaxf(o.y, 0.f);
                o.z = fmaxf(o.z, 0.f);
                o.w = fmaxf(o.w, 0.f);
            }
            *(float4*)(C + (long)grow * H + col0) = o;
        }
    }
}

// ---------------------------------------------------------------------------
extern "C" void kernel_launch(void* const* d_in, const int* in_sizes, int n_in,
                              void* d_out, int out_size, void* d_ws, size_t ws_size,
                              hipStream_t stream) {
    const float* x          = (const float*)d_in[0];
    const int*   edge_index = (const int*)  d_in[1];
    const int*   edge_attr  = (const int*)  d_in[2];
    const float* emb        = (const float*)d_in[3];
    const float* We         = (const float*)d_in[4];
    const float* be         = (const float*)d_in[5];
    const float* W1         = (const float*)d_in[6];
    const float* b1         = (const float*)d_in[7];
    const float* W2         = (const float*)d_in[8];
    const float* b2         = (const float*)d_in[9];
    const float* eps        = (const float*)d_in[10];
    float* out = (float*)d_out;

    char* ws = (char*)d_ws;
    size_t off = 0;
    float* proj    = (float*)(ws + off); off += (size_t)NTYPES * H * 4;          // 8 KB
    int*   count   = (int*)  (ws + off); off += (size_t)NNODES * 4;              // 200 KB
    int*   offsets = (int*)  (ws + off); off += (size_t)(NNODES + 4) * 4;        // 200 KB
    int*   cursor  = (int*)  (ws + off); off += (size_t)NNODES * 4;              // 200 KB
    int*   bsum    = (int*)  (ws + off); off += 64 * 4;
    int*   boff    = (int*)  (ws + off); off += 64 * 4;
    unsigned int* packed = (unsigned int*)(ws + off); off += (size_t)NEDGES * 4; // 2.56 MB
    float* z       = (float*)(ws + off); off += (size_t)NNODES * H * 4;          // 25.6 MB

    hipMemsetAsync(count, 0, (size_t)NNODES * sizeof(int), stream);

    proj_kernel<<<(NTYPES * H + 255) / 256, 256, 0, stream>>>(emb, We, be, proj);

    hist_kernel<<<(NEDGES + 255) / 256, 256, 0, stream>>>(edge_index, count);

    scan_s1<<<NSB, 256, 0, stream>>>(count, bsum);
    scan_s2<<<1, 64, 0, stream>>>(bsum, boff, offsets);
    scan_s3<<<NSB, 256, 0, stream>>>(count, boff, offsets, cursor);

    bucket_kernel<<<(NEDGES + 255) / 256, 256, 0, stream>>>(
        edge_index, edge_attr, cursor, packed);

    aggr_z_kernel<<<(NNODES + 3) / 4, 256, 0, stream>>>(
        x, offsets, packed, proj, eps, z);

    int gblocks = (NNODES + 31) / 32;
    mlp_kernel<true ><<<gblocks, 256, 0, stream>>>(z, W1, b1, z);    // in-place
    mlp_kernel<false><<<gblocks, 256, 0, stream>>>(z, W2, b2, out);
}

// Round 4
// 241.837 us; speedup vs baseline: 5.1970x; 1.2449x over previous
//
#include <hip/hip_runtime.h>

#define H       128
#define NNODES  50000
#define NEDGES  640000
#define NTYPES  16
#define EDIM    8

#define SCAN_CHUNK 1024
#define NSB ((NNODES + SCAN_CHUNK - 1) / SCAN_CHUNK)   // 49

typedef __attribute__((ext_vector_type(8))) __bf16 bf16x8;
typedef __attribute__((ext_vector_type(4))) float  f32x4;

// round-to-nearest-even float -> bf16 bits
__device__ __forceinline__ unsigned short f2bf(float f) {
    unsigned int u = __float_as_uint(f);
    u += 0x7fffu + ((u >> 16) & 1u);
    return (unsigned short)(u >> 16);
}

// ---------------------------------------------------------------------------
// proj[t][f] = be[f] + sum_d emb[t][d] * We[d][f]   (16 x 128 lookup table)
// ---------------------------------------------------------------------------
__global__ void proj_kernel(const float* __restrict__ emb,
                            const float* __restrict__ We,
                            const float* __restrict__ be,
                            float* __restrict__ proj) {
    int id = blockIdx.x * blockDim.x + threadIdx.x;   // 0..2047
    if (id >= NTYPES * H) return;
    int t = id >> 7;
    int f = id & (H - 1);
    float acc = be[f];
#pragma unroll
    for (int d = 0; d < EDIM; ++d)
        acc += emb[t * EDIM + d] * We[d * H + f];
    proj[id] = acc;
}

// ---------------------------------------------------------------------------
// histogram of dst degree
// ---------------------------------------------------------------------------
__global__ void hist_kernel(const int* __restrict__ edge_index,
                            int* __restrict__ count) {
    int e = blockIdx.x * blockDim.x + threadIdx.x;
    if (e >= NEDGES) return;
    int dst = edge_index[NEDGES + e];
    atomicAdd(&count[dst], 1);
}

// ---------------------------------------------------------------------------
// hierarchical scan
// ---------------------------------------------------------------------------
__global__ __launch_bounds__(256) void scan_s1(const int* __restrict__ count,
                                               int* __restrict__ bsum) {
    __shared__ int red[256];
    const int t = threadIdx.x;
    const int base = blockIdx.x * SCAN_CHUNK + t * 4;
    int s = 0;
    if (base + 3 < NNODES) {
        int4 v = *(const int4*)(count + base);
        s = v.x + v.y + v.z + v.w;
    } else {
#pragma unroll
        for (int j = 0; j < 4; ++j)
            if (base + j < NNODES) s += count[base + j];
    }
    red[t] = s;
    __syncthreads();
    for (int off = 128; off > 0; off >>= 1) {
        if (t < off) red[t] += red[t + off];
        __syncthreads();
    }
    if (t == 0) bsum[blockIdx.x] = red[0];
}

__global__ void scan_s2(const int* __restrict__ bsum,
                        int* __restrict__ boff,
                        int* __restrict__ offsets) {
    int lane = threadIdx.x;   // 64 threads, single wave
    int v = (lane < NSB) ? bsum[lane] : 0;
    int incl = v;
#pragma unroll
    for (int off = 1; off < 64; off <<= 1) {
        int u = __shfl_up(incl, off, 64);
        if (lane >= off) incl += u;
    }
    if (lane < NSB) boff[lane] = incl - v;
    if (lane == 63) offsets[NNODES] = incl;
}

__global__ __launch_bounds__(256) void scan_s3(const int* __restrict__ count,
                                               const int* __restrict__ boff,
                                               int* __restrict__ offsets,
                                               int* __restrict__ cursor) {
    __shared__ int tsum[256];
    const int t = threadIdx.x;
    const int base = blockIdx.x * SCAN_CHUNK + t * 4;

    int c[4] = {0, 0, 0, 0};
    if (base + 3 < NNODES) {
        int4 v = *(const int4*)(count + base);
        c[0] = v.x; c[1] = v.y; c[2] = v.z; c[3] = v.w;
    } else {
#pragma unroll
        for (int j = 0; j < 4; ++j)
            if (base + j < NNODES) c[j] = count[base + j];
    }
    int s = c[0] + c[1] + c[2] + c[3];
    tsum[t] = s;
    __syncthreads();
    for (int off = 1; off < 256; off <<= 1) {
        int v = (t >= off) ? tsum[t - off] : 0;
        __syncthreads();
        tsum[t] += v;
        __syncthreads();
    }
    int run = boff[blockIdx.x] + tsum[t] - s;
    int4 o;
    o.x = run;
    o.y = run + c[0];
    o.z = run + c[0] + c[1];
    o.w = run + c[0] + c[1] + c[2];
    if (base + 3 < NNODES) {
        *(int4*)(offsets + base) = o;
        *(int4*)(cursor  + base) = o;
    } else {
        int oo[4] = {o.x, o.y, o.z, o.w};
#pragma unroll
        for (int j = 0; j < 4; ++j)
            if (base + j < NNODES) { offsets[base + j] = oo[j]; cursor[base + j] = oo[j]; }
    }
}

// ---------------------------------------------------------------------------
// bucket edges by dst: packed[pos] = src | (type << 16)   (src < 2^16)
// ---------------------------------------------------------------------------
__global__ void bucket_kernel(const int* __restrict__ edge_index,
                              const int* __restrict__ edge_attr,
                              int* __restrict__ cursor,
                              unsigned int* __restrict__ packed) {
    int e = blockIdx.x * blockDim.x + threadIdx.x;
    if (e >= NEDGES) return;
    int src = edge_index[e];
    int dst = edge_index[NEDGES + e];
    int a0 = edge_attr[e * 3 + 0];
    int a1 = edge_attr[e * 3 + 1];
    int a2 = edge_attr[e * 3 + 2];
    unsigned int h = (unsigned int)(a0 + 3 * a1 + 7 * a2) & (NTYPES - 1);
    int pos = atomicAdd(&cursor[dst], 1);
    packed[pos] = (unsigned int)src | (h << 16);
}

// ---------------------------------------------------------------------------
// pack W (fp32 [k][n]) into MFMA B-fragment order, bf16:
// P[c][kc][lane][j] = W[kc*32 + (lane>>4)*8 + j][c*16 + (lane&15)]
// id<2048 -> W1, else W2
// ---------------------------------------------------------------------------
__global__ void pack_w_kernel(const float* __restrict__ W1,
                              const float* __restrict__ W2,
                              unsigned short* __restrict__ w1p,
                              unsigned short* __restrict__ w2p) {
    int id = blockIdx.x * blockDim.x + threadIdx.x;   // 0..4095
    const float* W = (id < 2048) ? W1 : W2;
    unsigned short* P = (id < 2048) ? w1p : w2p;
    int q = id & 2047;
    int lane = q & 63;
    int kc = (q >> 6) & 3;
    int c  = q >> 8;
    int n = c * 16 + (lane & 15);
    int kbase = kc * 32 + (lane >> 4) * 8;
#pragma unroll
    for (int j = 0; j < 8; ++j)
        P[q * 8 + j] = f2bf(W[(kbase + j) * H + n]);
}

// ---------------------------------------------------------------------------
// one wave per node: acc = sum_j relu(x[src_j] + proj[type_j]);
// z = (1+eps)*x[n] + acc, emitted as bf16.
// ---------------------------------------------------------------------------
__global__ __launch_bounds__(256) void aggr_z_kernel(
        const float* __restrict__ x,
        const int* __restrict__ offsets,
        const unsigned int* __restrict__ packed,
        const float* __restrict__ proj,
        const float* __restrict__ epsp,
        unsigned short* __restrict__ zb) {
    __shared__ float projL[NTYPES * H];   // 8 KB
    const int t = threadIdx.x;
#pragma unroll
    for (int i = 0; i < 2; ++i)
        ((float4*)projL)[t + i * 256] = ((const float4*)proj)[t + i * 256];
    __syncthreads();

    const int node = blockIdx.x * 4 + (t >> 6);
    if (node >= NNODES) return;
    const int lane = t & 63;

    const int s = offsets[node];
    const int e = offsets[node + 1];

    float ax = 0.0f, ay = 0.0f;
    int j = s;
    for (; j + 1 < e; j += 2) {
        unsigned int p0 = packed[j];
        unsigned int p1 = packed[j + 1];
        const float2 x0 = *(const float2*)(x + (long)(p0 & 0xffffu) * H + lane * 2);
        const float2 x1 = *(const float2*)(x + (long)(p1 & 0xffffu) * H + lane * 2);
        const float2 q0 = *(const float2*)(projL + (p0 >> 16) * H + lane * 2);
        const float2 q1 = *(const float2*)(projL + (p1 >> 16) * H + lane * 2);
        ax += fmaxf(x0.x + q0.x, 0.0f) + fmaxf(x1.x + q1.x, 0.0f);
        ay += fmaxf(x0.y + q0.y, 0.0f) + fmaxf(x1.y + q1.y, 0.0f);
    }
    if (j < e) {
        unsigned int p0 = packed[j];
        const float2 x0 = *(const float2*)(x + (long)(p0 & 0xffffu) * H + lane * 2);
        const float2 q0 = *(const float2*)(projL + (p0 >> 16) * H + lane * 2);
        ax += fmaxf(x0.x + q0.x, 0.0f);
        ay += fmaxf(x0.y + q0.y, 0.0f);
    }

    const float scale = 1.0f + *epsp;
    const float2 xo = *(const float2*)(x + (long)node * H + lane * 2);
    float zx = scale * xo.x + ax;
    float zy = scale * xo.y + ay;
    unsigned int p = (unsigned int)f2bf(zx) | ((unsigned int)f2bf(zy) << 16);
    *(unsigned int*)(zb + (size_t)node * H + lane * 2) = p;
}

// ---------------------------------------------------------------------------
// fused MLP: out = relu(z @ W1 + b1) @ W2 + b2, bf16 MFMA, fp32 accum.
// One wave owns 16 rows (50000 = 16*3125); 4 independent waves per block,
// each with a private padded LDS slab (16 x 136 bf16). No __syncthreads.
// B-frags read straight from packed global (L2-hot, 32 KB per layer).
// ---------------------------------------------------------------------------
__global__ __launch_bounds__(256) void fused_mlp_kernel(
        const unsigned short* __restrict__ zb,
        const unsigned short* __restrict__ w1p,
        const unsigned short* __restrict__ w2p,
        const float* __restrict__ b1,
        const float* __restrict__ b2,
        float* __restrict__ out) {
    __shared__ unsigned short tile[4][16 * 136];   // 17.4 KB
    const int t = threadIdx.x;
    const int w = t >> 6, lane = t & 63;
    const int row0 = blockIdx.x * 64 + w * 16;
    if (row0 >= NNODES) return;
    unsigned short* T = tile[w];
    const int m = lane & 15, quad = lane >> 4;

    // stage this wave's 16 z-rows (4 KB contiguous) into padded LDS
    {
        const unsigned short* src = zb + (size_t)row0 * H;
#pragma unroll
        for (int i = 0; i < 4; ++i) {
            int g = lane * 8 + i * 512;            // element idx in 16x128
            int4 v = *(const int4*)(src + g);
            int r = g >> 7, cc = g & 127;
            *(int4*)(T + r * 136 + cc) = v;
        }
    }

    // A-frags for GEMM1: A[m][k], k = quad*8 + j + kc*32
    bf16x8 a[4];
#pragma unroll
    for (int kc = 0; kc < 4; ++kc)
        a[kc] = *(const bf16x8*)(T + m * 136 + kc * 32 + quad * 8);

    // GEMM1 + bias + relu -> h (bf16) back into the same LDS slab
    const bf16x8* w1f = (const bf16x8*)w1p;
#pragma unroll
    for (int c = 0; c < 8; ++c) {
        f32x4 acc = {0.f, 0.f, 0.f, 0.f};
#pragma unroll
        for (int kc = 0; kc < 4; ++kc)
            acc = __builtin_amdgcn_mfma_f32_16x16x32_bf16(
                      a[kc], w1f[(c * 4 + kc) * 64 + lane], acc, 0, 0, 0);
        int col = c * 16 + m;                      // C layout: col = lane&15
        float bias = b1[col];
#pragma unroll
        for (int r = 0; r < 4; ++r) {              // row = quad*4 + r
            float v = fmaxf(acc[r] + bias, 0.0f);
            T[(quad * 4 + r) * 136 + col] = f2bf(v);
        }
    }

    // A-frags for GEMM2 (h)
    bf16x8 ha[4];
#pragma unroll
    for (int kc = 0; kc < 4; ++kc)
        ha[kc] = *(const bf16x8*)(T + m * 136 + kc * 32 + quad * 8);

    // GEMM2 + bias -> out (fp32)
    const bf16x8* w2f = (const bf16x8*)w2p;
#pragma unroll
    for (int c = 0; c < 8; ++c) {
        f32x4 acc = {0.f, 0.f, 0.f, 0.f};
#pragma unroll
        for (int kc = 0; kc < 4; ++kc)
            acc = __builtin_amdgcn_mfma_f32_16x16x32_bf16(
                      ha[kc], w2f[(c * 4 + kc) * 64 + lane], acc, 0, 0, 0);
        int col = c * 16 + m;
        float bias = b2[col];
#pragma unroll
        for (int r = 0; r < 4; ++r)
            out[(size_t)(row0 + quad * 4 + r) * H + col] = acc[r] + bias;
    }
}

// ---------------------------------------------------------------------------
extern "C" void kernel_launch(void* const* d_in, const int* in_sizes, int n_in,
                              void* d_out, int out_size, void* d_ws, size_t ws_size,
                              hipStream_t stream) {
    const float* x          = (const float*)d_in[0];
    const int*   edge_index = (const int*)  d_in[1];
    const int*   edge_attr  = (const int*)  d_in[2];
    const float* emb        = (const float*)d_in[3];
    const float* We         = (const float*)d_in[4];
    const float* be         = (const float*)d_in[5];
    const float* W1         = (const float*)d_in[6];
    const float* b1         = (const float*)d_in[7];
    const float* W2         = (const float*)d_in[8];
    const float* b2         = (const float*)d_in[9];
    const float* eps        = (const float*)d_in[10];
    float* out = (float*)d_out;

    char* ws = (char*)d_ws;
    size_t off = 0;
    float* proj    = (float*)(ws + off); off += (size_t)NTYPES * H * 4;          // 8 KB
    int*   count   = (int*)  (ws + off); off += (size_t)NNODES * 4;              // 200 KB
    int*   offsets = (int*)  (ws + off); off += (size_t)(NNODES + 4) * 4;
    int*   cursor  = (int*)  (ws + off); off += (size_t)NNODES * 4;
    int*   bsum    = (int*)  (ws + off); off += 64 * 4;
    int*   boff    = (int*)  (ws + off); off += 64 * 4;
    unsigned int* packed = (unsigned int*)(ws + off); off += (size_t)NEDGES * 4; // 2.56 MB
    unsigned short* zb   = (unsigned short*)(ws + off); off += (size_t)NNODES * H * 2; // 12.8 MB
    unsigned short* w1p  = (unsigned short*)(ws + off); off += 2048 * 8 * 2;     // 32 KB
    unsigned short* w2p  = (unsigned short*)(ws + off); off += 2048 * 8 * 2;     // 32 KB

    hipMemsetAsync(count, 0, (size_t)NNODES * sizeof(int), stream);

    proj_kernel<<<(NTYPES * H + 255) / 256, 256, 0, stream>>>(emb, We, be, proj);

    pack_w_kernel<<<16, 256, 0, stream>>>(W1, W2, w1p, w2p);

    hist_kernel<<<(NEDGES + 255) / 256, 256, 0, stream>>>(edge_index, count);

    scan_s1<<<NSB, 256, 0, stream>>>(count, bsum);
    scan_s2<<<1, 64, 0, stream>>>(bsum, boff, offsets);
    scan_s3<<<NSB, 256, 0, stream>>>(count, boff, offsets, cursor);

    bucket_kernel<<<(NEDGES + 255) / 256, 256, 0, stream>>>(
        edge_index, edge_attr, cursor, packed);

    aggr_z_kernel<<<(NNODES + 3) / 4, 256, 0, stream>>>(
        x, offsets, packed, proj, eps, zb);

    fused_mlp_kernel<<<(NNODES + 63) / 64, 256, 0, stream>>>(
        zb, w1p, w2p, b1, b2, out);
}